// Round 13
// baseline (174.322 us; speedup 1.0000x reference)
//
#include <hip/hip_runtime.h>
#include <hip/hip_bf16.h>
#include <stdint.h>

#define BTOT 4096
#define RR   64
#define DIMD 128
#define WROW 40   /* wave-buffer row stride in shorts (80 B): bank-friendly */

typedef short s16x8 __attribute__((ext_vector_type(8)));
typedef float f32x4 __attribute__((ext_vector_type(4)));

__device__ __forceinline__ unsigned short f2bf(float x) {
  __hip_bfloat16 h = __float2bfloat16(x);
  return __builtin_bit_cast(unsigned short, h);
}
__device__ __forceinline__ float bf2f(unsigned short u) {
  unsigned int v = ((unsigned int)u) << 16;
  return __builtin_bit_cast(float, v);
}

// ---------------------------------------------------------------------------
// Pre-kernel: qproj[b,k] = sum_d query_r[b,d]*W1[k,128+d] + b1[k]  (fp32),
// offset_emb passthrough, and blocks 0/1 emit XOR-swizzled bf16 copies of
// W1a / W2 into ws.  Swizzle: element (k,d) at k*128 + (d ^ ((k&7)<<3)).
// ---------------------------------------------------------------------------
__global__ __launch_bounds__(256) void prep_kernel(
    const float* __restrict__ W1, const float* __restrict__ b1,
    const float* __restrict__ query_r, const float* __restrict__ W2,
    const float* __restrict__ offset_emb,
    float* __restrict__ qproj, unsigned short* __restrict__ w1a_swz,
    unsigned short* __restrict__ w2_swz, float* __restrict__ out)
{
  __shared__ float w1b[128 * 132];   // +4 pad
  __shared__ float qrs[256];
  const int tid = threadIdx.x;

  { // offset_emb passthrough (1 float4 per thread; 512 blocks cover 4096x128)
    const size_t ob = (size_t)blockIdx.x * 8 * DIMD + (size_t)tid * 4;
    *reinterpret_cast<float4*>(out + (size_t)BTOT * DIMD + ob) =
        *reinterpret_cast<const float4*>(offset_emb + ob);
  }
  { // stage W1b fp32 into padded LDS
    const int k = tid >> 1, d0 = (tid & 1) * 64;
    const float* src = W1 + k * 256 + 128 + d0;
    float* dst = &w1b[k * 132 + d0];
    #pragma unroll
    for (int i = 0; i < 64; i += 4)
      *reinterpret_cast<float4*>(dst + i) = *reinterpret_cast<const float4*>(src + i);
  }
  if (blockIdx.x < 2) { // swizzled bf16 weights
    const float* Wsrc = (blockIdx.x == 0) ? W1 : W2;
    unsigned short* dstw = (blockIdx.x == 0) ? w1a_swz : w2_swz;
    const int stride = (blockIdx.x == 0) ? 256 : 128;
    for (int i = tid; i < 128 * 128; i += 256) {
      const int k = i >> 7, d = i & 127;
      dstw[k * 128 + (d ^ ((k & 7) << 3))] = f2bf(Wsrc[k * stride + d]);
    }
  }
  __syncthreads();

  const int b0 = blockIdx.x * 8;
  const int k = tid & 127, bh = tid >> 7;
  for (int p = 0; p < 4; ++p) {
    const int b = b0 + p * 2;
    qrs[tid] = query_r[(size_t)(b + bh) * DIMD + k];
    __syncthreads();
    float acc = b1[k];
    const float* qq = &qrs[bh * 128];
    const float* wr = &w1b[k * 132];
    #pragma unroll
    for (int d = 0; d < 128; d += 4) {
      float4 wv = *reinterpret_cast<const float4*>(wr + d);
      float4 qv = *reinterpret_cast<const float4*>(qq + d);
      acc = fmaf(wv.x, qv.x, acc); acc = fmaf(wv.y, qv.y, acc);
      acc = fmaf(wv.z, qv.z, acc); acc = fmaf(wv.w, qv.w, acc);
    }
    qproj[(size_t)(b + bh) * DIMD + k] = acc;
    __syncthreads();
  }
}

// ---------------------------------------------------------------------------
// Main kernel: 256 blocks x 512 threads (8 waves); each wave owns TWO b's
// SEQUENTIALLY (single chain). Body = R8's proven quarter structure (96 VGPR,
// ~200 MB FETCH, WROW=40 bank-friendly wave buffer, weights in LDS) with two
// changes, isolating the latency diagnosis:
//  (1) ALL asm lgkmcnt(0)/"memory" fences removed -- R11 proved per-wave DS
//      in-order + LLVM's may-alias LDS ordering + compiler-precise lgkmcnt
//      waits are sufficient for correctness; the fences were blocking global
//      load hoisting (each quarter ate full memory latency serially).
//  (2) Explicit depth-1 QUARTER prefetch: consume prefetched quarter ->
//      issue next quarter's 6 float4 loads -> MFMA. Transient liveness =
//      one quarter (24 VGPR), fitting bare-512's observed 128-VGPR cap
//      (R12's dual-chain needed ~200 -> spilled). The flat chain crosses
//      GEMM2/bias phases and the b-boundary, so one load batch is always
//      in flight.
// Grid 256 = exactly 1 block/CU: weights staged once, no cold second round.
// LDS = 64 KB weights + 8 x 1.25 KB = 74 KB.
// ---------------------------------------------------------------------------
__global__ __launch_bounds__(512) void main_kernel(
    const float* __restrict__ query_emb,
    const float* __restrict__ refer_embs, const float* __restrict__ refer_r,
    const float* __restrict__ start_embs, const float* __restrict__ b2,
    const float* __restrict__ qproj, const unsigned short* __restrict__ w1a_swz,
    const unsigned short* __restrict__ w2_swz, float* __restrict__ out)
{
  __shared__ unsigned short lds_w1a[128 * 128];   // 32 KB, swizzled
  __shared__ unsigned short lds_w2[128 * 128];    // 32 KB, swizzled
  __shared__ unsigned short wbuf[8][16 * WROW];   // 1.25 KB per wave

  const int tid  = threadIdx.x;
  const int wave = tid >> 6;
  const int lane = tid & 63;
  const int g    = lane >> 4;   // k-group
  const int c    = lane & 15;   // row/col-in-tile

  { // stage swizzled weights (linear uint4 copy; swizzle pre-applied in ws)
    const uint4* s1 = reinterpret_cast<const uint4*>(w1a_swz);
    const uint4* s2 = reinterpret_cast<const uint4*>(w2_swz);
    uint4* d1 = reinterpret_cast<uint4*>(lds_w1a);
    uint4* d2 = reinterpret_cast<uint4*>(lds_w2);
    #pragma unroll
    for (int i = 0; i < 4; ++i) {
      d1[tid + 512 * i] = s1[tid + 512 * i];
      d2[tid + 512 * i] = s2[tid + 512 * i];
    }
  }
  __syncthreads();   // the ONLY barrier

  unsigned short* mybuf = &wbuf[wave][0];
  const int srl = lane >> 2;           // staging local row 0..15
  const int q   = lane & 3;            // staging quarter-of-row (8 floats)
  const int swc = (c & 7) << 3;        // weight swizzle for row nt*16+c
  const int rl4 = 4 * g;

  const int bA = blockIdx.x * 16 + wave * 2;   // this wave's first b

  float b2v[8];
  #pragma unroll
  for (int nt = 0; nt < 8; ++nt) b2v[nt] = b2[nt * 16 + c];

  // prefetch registers: exactly one quarter (6 x float4 = 24 VGPR)
  float4 Prv0, Prv1, Pev0, Pev1, Psv0, Psv1;

#define LOADQ(fq) do {                                                        \
    const int bb_ = (fq) >> 4, it_ = ((fq) >> 2) & 3, Q_ = (fq) & 3;          \
    const size_t gb_ =                                                        \
        ((size_t)(bA + bb_) * RR + it_ * 16 + srl) * DIMD + Q_ * 32 + q * 8;  \
    Prv0 = *reinterpret_cast<const float4*>(refer_r    + gb_);                \
    Prv1 = *reinterpret_cast<const float4*>(refer_r    + gb_ + 4);            \
    Pev0 = *reinterpret_cast<const float4*>(refer_embs + gb_);                \
    Pev1 = *reinterpret_cast<const float4*>(refer_embs + gb_ + 4);            \
    Psv0 = *reinterpret_cast<const float4*>(start_embs + gb_);                \
    Psv1 = *reinterpret_cast<const float4*>(start_embs + gb_ + 4);            \
  } while (0)

  LOADQ(0);   // prologue

  #pragma unroll
  for (int bb = 0; bb < 2; ++bb) {
    const int b = bA + bb;

    float qn[8], acc[8];
    #pragma unroll
    for (int nt = 0; nt < 8; ++nt) {
      qn[nt]  = qproj[(size_t)b * DIMD + nt * 16 + c];
      acc[nt] = 0.f;
    }

    for (int it = 0; it < 4; ++it) {
      uint4 bp[4];
      f32x4 Ch[8];
      #pragma unroll
      for (int nt = 0; nt < 8; ++nt) Ch[nt] = (f32x4){qn[nt], qn[nt], qn[nt], qn[nt]};

      // ============ GEMM1 (four 32-wide d-quarters, pipelined) ============
      #pragma unroll
      for (int Q = 0; Q < 4; ++Q) {
        { // consume prefetched quarter: stage refer_r (one uint4 per lane)
          union { unsigned short u[8]; uint4 v; } pk;
          pk.u[0] = f2bf(Prv0.x); pk.u[1] = f2bf(Prv0.y);
          pk.u[2] = f2bf(Prv0.z); pk.u[3] = f2bf(Prv0.w);
          pk.u[4] = f2bf(Prv1.x); pk.u[5] = f2bf(Prv1.y);
          pk.u[6] = f2bf(Prv1.z); pk.u[7] = f2bf(Prv1.w);
          *reinterpret_cast<uint4*>(&mybuf[srl * WROW + q * 8]) = pk.v;
        }
        { // bias quarter = ev - sv - rv, packed bf16 (row layout, in regs)
          union { unsigned short u[8]; uint4 v; } pk;
          pk.u[0] = f2bf(Pev0.x - Psv0.x - Prv0.x);
          pk.u[1] = f2bf(Pev0.y - Psv0.y - Prv0.y);
          pk.u[2] = f2bf(Pev0.z - Psv0.z - Prv0.z);
          pk.u[3] = f2bf(Pev0.w - Psv0.w - Prv0.w);
          pk.u[4] = f2bf(Pev1.x - Psv1.x - Prv1.x);
          pk.u[5] = f2bf(Pev1.y - Psv1.y - Prv1.y);
          pk.u[6] = f2bf(Pev1.z - Psv1.z - Prv1.z);
          pk.u[7] = f2bf(Pev1.w - Psv1.w - Prv1.w);
          bp[Q] = pk.v;
        }
        // issue next quarter's loads (old P dead, new P born: 24 VGPR flat)
        const int fq = bb * 16 + it * 4 + Q;
        if (fq + 1 < 32) { LOADQ(fq + 1); }
        // A-frag + 8 MFMA
        const s16x8 af = *reinterpret_cast<const s16x8*>(&mybuf[c * WROW + g * 8]);
        #pragma unroll
        for (int nt = 0; nt < 8; ++nt) {
          s16x8 wf = *reinterpret_cast<const s16x8*>(
              &lds_w1a[(nt * 16 + c) * DIMD + ((Q * 32 + g * 8) ^ swc)]);
          Ch[nt] = __builtin_amdgcn_mfma_f32_16x16x32_bf16(af, wf, Ch[nt], 0, 0, 0);
        }
      }

      // ============ GEMM2 (four 32-wide k_hid-quarters) ============
      f32x4 Ca[8];
      #pragma unroll
      for (int nt = 0; nt < 8; ++nt) Ca[nt] = (f32x4){b2v[nt], b2v[nt], b2v[nt], b2v[nt]};
      #pragma unroll
      for (int Q = 0; Q < 4; ++Q) {
        #pragma unroll
        for (int ntl = 0; ntl < 2; ++ntl)
          #pragma unroll
          for (int r = 0; r < 4; ++r)
            mybuf[(rl4 + r) * WROW + ntl * 16 + c] =
                f2bf(fmaxf(Ch[2 * Q + ntl][r], 0.f));
        const s16x8 hf = *reinterpret_cast<const s16x8*>(&mybuf[c * WROW + g * 8]);
        #pragma unroll
        for (int nt = 0; nt < 8; ++nt) {
          s16x8 wf = *reinterpret_cast<const s16x8*>(
              &lds_w2[(nt * 16 + c) * DIMD + ((Q * 32 + g * 8) ^ swc)]);
          Ca[nt] = __builtin_amdgcn_mfma_f32_16x16x32_bf16(hf, wf, Ca[nt], 0, 0, 0);
        }
      }

      // ============ bias dot + reduce (four quarters) ============
      #pragma unroll
      for (int Q = 0; Q < 4; ++Q) {
        *reinterpret_cast<uint4*>(&mybuf[srl * WROW + q * 8]) = bp[Q];
        #pragma unroll
        for (int ntl = 0; ntl < 2; ++ntl) {
          const int nt = 2 * Q + ntl;
          float s = 0.f;
          #pragma unroll
          for (int r = 0; r < 4; ++r) {
            const float bcv = bf2f(mybuf[(rl4 + r) * WROW + ntl * 16 + c]);
            s = fmaf(Ca[nt][r], bcv, s);
          }
          s += __shfl_xor(s, 16);
          s += __shfl_xor(s, 32);
          acc[nt] += s;
        }
      }
    }

    // ---- epilogue for this b
    if (lane < 16) {
      #pragma unroll
      for (int nt = 0; nt < 8; ++nt)
        out[(size_t)b * DIMD + nt * 16 + c] =
            query_emb[(size_t)b * DIMD + nt * 16 + c] + acc[nt];
    }
  }
#undef LOADQ
}

extern "C" void kernel_launch(void* const* d_in, const int* in_sizes, int n_in,
                              void* d_out, int out_size, void* d_ws, size_t ws_size,
                              hipStream_t stream) {
  const float* query_emb  = (const float*)d_in[0];
  const float* offset_emb = (const float*)d_in[1];
  const float* refer_embs = (const float*)d_in[2];
  const float* query_r    = (const float*)d_in[3];
  const float* refer_r    = (const float*)d_in[4];
  const float* start_embs = (const float*)d_in[5];
  const float* W1 = (const float*)d_in[6];
  const float* b1 = (const float*)d_in[7];
  const float* W2 = (const float*)d_in[8];
  const float* b2 = (const float*)d_in[9];
  float* out = (float*)d_out;

  float* qproj = (float*)d_ws;                       // 4096*128 f32 = 2 MB
  unsigned short* w1a_swz =
      (unsigned short*)((char*)d_ws + (size_t)BTOT * DIMD * sizeof(float));
  unsigned short* w2_swz = w1a_swz + 128 * 128;      // +32 KB each

  hipLaunchKernelGGL(prep_kernel, dim3(512), dim3(256), 0, stream,
                     W1, b1, query_r, W2, offset_emb, qproj, w1a_swz, w2_swz, out);
  hipLaunchKernelGGL(main_kernel, dim3(256), dim3(512), 0, stream,
                     query_emb, refer_embs, refer_r, start_embs,
                     b2, qproj, w1a_swz, w2_swz, out);
}

// Round 14
// 106.839 us; speedup vs baseline: 1.6316x; 1.6316x over previous
//
#include <hip/hip_runtime.h>
#include <hip/hip_bf16.h>
#include <stdint.h>

#define BTOT 4096
#define RR   64
#define DIMD 128
#define WROW 40   /* wave-buffer row stride in shorts (80 B): bank-friendly */

typedef short s16x8 __attribute__((ext_vector_type(8)));
typedef float f32x4 __attribute__((ext_vector_type(4)));

__device__ __forceinline__ unsigned short f2bf(float x) {
  __hip_bfloat16 h = __float2bfloat16(x);
  return __builtin_bit_cast(unsigned short, h);
}
__device__ __forceinline__ float bf2f(unsigned short u) {
  unsigned int v = ((unsigned int)u) << 16;
  return __builtin_bit_cast(float, v);
}

// ---------------------------------------------------------------------------
// Pre-kernel: qproj[b,k] = sum_d query_r[b,d]*W1[k,128+d] + b1[k]  (fp32),
// offset_emb passthrough, and blocks 0/1 emit XOR-swizzled bf16 copies of
// W1a / W2 into ws.  Swizzle: element (k,d) at k*128 + (d ^ ((k&7)<<3)).
// ---------------------------------------------------------------------------
__global__ __launch_bounds__(256) void prep_kernel(
    const float* __restrict__ W1, const float* __restrict__ b1,
    const float* __restrict__ query_r, const float* __restrict__ W2,
    const float* __restrict__ offset_emb,
    float* __restrict__ qproj, unsigned short* __restrict__ w1a_swz,
    unsigned short* __restrict__ w2_swz, float* __restrict__ out)
{
  __shared__ float w1b[128 * 132];   // +4 pad
  __shared__ float qrs[256];
  const int tid = threadIdx.x;

  { // offset_emb passthrough (1 float4 per thread; 512 blocks cover 4096x128)
    const size_t ob = (size_t)blockIdx.x * 8 * DIMD + (size_t)tid * 4;
    *reinterpret_cast<float4*>(out + (size_t)BTOT * DIMD + ob) =
        *reinterpret_cast<const float4*>(offset_emb + ob);
  }
  { // stage W1b fp32 into padded LDS
    const int k = tid >> 1, d0 = (tid & 1) * 64;
    const float* src = W1 + k * 256 + 128 + d0;
    float* dst = &w1b[k * 132 + d0];
    #pragma unroll
    for (int i = 0; i < 64; i += 4)
      *reinterpret_cast<float4*>(dst + i) = *reinterpret_cast<const float4*>(src + i);
  }
  if (blockIdx.x < 2) { // swizzled bf16 weights
    const float* Wsrc = (blockIdx.x == 0) ? W1 : W2;
    unsigned short* dstw = (blockIdx.x == 0) ? w1a_swz : w2_swz;
    const int stride = (blockIdx.x == 0) ? 256 : 128;
    for (int i = tid; i < 128 * 128; i += 256) {
      const int k = i >> 7, d = i & 127;
      dstw[k * 128 + (d ^ ((k & 7) << 3))] = f2bf(Wsrc[k * stride + d]);
    }
  }
  __syncthreads();

  const int b0 = blockIdx.x * 8;
  const int k = tid & 127, bh = tid >> 7;
  for (int p = 0; p < 4; ++p) {
    const int b = b0 + p * 2;
    qrs[tid] = query_r[(size_t)(b + bh) * DIMD + k];
    __syncthreads();
    float acc = b1[k];
    const float* qq = &qrs[bh * 128];
    const float* wr = &w1b[k * 132];
    #pragma unroll
    for (int d = 0; d < 128; d += 4) {
      float4 wv = *reinterpret_cast<const float4*>(wr + d);
      float4 qv = *reinterpret_cast<const float4*>(qq + d);
      acc = fmaf(wv.x, qv.x, acc); acc = fmaf(wv.y, qv.y, acc);
      acc = fmaf(wv.z, qv.z, acc); acc = fmaf(wv.w, qv.w, acc);
    }
    qproj[(size_t)(b + bh) * DIMD + k] = acc;
    __syncthreads();
  }
}

// ---------------------------------------------------------------------------
// Main kernel: R8 byte-for-byte (512 blocks x 512 threads, 1 b/wave, quarter
// structure, ALL lgkmcnt fences KEPT) + ONE change: bounded depth-1 quarter
// prefetch. The 2x2 matrix over {fences, prefetch} across R8/R11/R13 showed
// fence REMOVAL causes both pathologies (compiler over-hoisting -> 128-VGPR
// spill; stream reorder -> FETCH 200->350 MB). Fences pin order and liveness
// -- but they are lgkmcnt-only: global loads issued BEFORE a fence stay in
// flight ACROSS it (vmcnt wait lands at first use, next quarter). So each
// GEMM1 quarter: consume prefetched batch -> pack bias -> ISSUE next
// quarter's 6 loads -> fence -> af + 8 MFMA -> fence. The flat 16-quarter
// chain crosses GEMM2/bias (quarter 0 of iter i+1 in flight throughout).
// Adds exactly 24 VGPR (96 -> ~120, under the observed bare-512 cap of 128).
// LDS = 64 KB weights + 8 x 1.25 KB = 74 KB.
// ---------------------------------------------------------------------------
__global__ __launch_bounds__(512) void main_kernel(
    const float* __restrict__ query_emb,
    const float* __restrict__ refer_embs, const float* __restrict__ refer_r,
    const float* __restrict__ start_embs, const float* __restrict__ b2,
    const float* __restrict__ qproj, const unsigned short* __restrict__ w1a_swz,
    const unsigned short* __restrict__ w2_swz, float* __restrict__ out)
{
  __shared__ unsigned short lds_w1a[128 * 128];   // 32 KB, swizzled
  __shared__ unsigned short lds_w2[128 * 128];    // 32 KB, swizzled
  __shared__ unsigned short wbuf[8][16 * WROW];   // 1.25 KB per wave

  const int tid  = threadIdx.x;
  const int wave = tid >> 6;
  const int lane = tid & 63;
  const int g    = lane >> 4;   // k-group
  const int c    = lane & 15;   // row/col-in-tile

  { // stage swizzled weights (linear uint4 copy; swizzle pre-applied in ws)
    const uint4* s1 = reinterpret_cast<const uint4*>(w1a_swz);
    const uint4* s2 = reinterpret_cast<const uint4*>(w2_swz);
    uint4* d1 = reinterpret_cast<uint4*>(lds_w1a);
    uint4* d2 = reinterpret_cast<uint4*>(lds_w2);
    #pragma unroll
    for (int i = 0; i < 4; ++i) {
      d1[tid + 512 * i] = s1[tid + 512 * i];
      d2[tid + 512 * i] = s2[tid + 512 * i];
    }
  }
  __syncthreads();   // the ONLY barrier

  unsigned short* mybuf = &wbuf[wave][0];
  const int srl = lane >> 2;           // staging local row 0..15
  const int q   = lane & 3;            // staging quarter-of-row (8 floats)
  const int swc = (c & 7) << 3;        // weight swizzle for row nt*16+c
  const int rl4 = 4 * g;

  const int b = blockIdx.x * 8 + wave;  // this wave's b

  float qn[8], b2v[8], acc[8];
  #pragma unroll
  for (int nt = 0; nt < 8; ++nt) {
    qn[nt]  = qproj[(size_t)b * DIMD + nt * 16 + c];
    b2v[nt] = b2[nt * 16 + c];
    acc[nt] = 0.f;
  }

  // prefetch registers: exactly one quarter (6 x float4 = 24 VGPR)
  float4 Prv0, Prv1, Pev0, Pev1, Psv0, Psv1;

#define LOADQ(fq) do {                                                        \
    const int it_ = (fq) >> 2, Q_ = (fq) & 3;                                 \
    const size_t gb_ =                                                        \
        ((size_t)b * RR + it_ * 16 + srl) * DIMD + Q_ * 32 + q * 8;           \
    Prv0 = *reinterpret_cast<const float4*>(refer_r    + gb_);                \
    Prv1 = *reinterpret_cast<const float4*>(refer_r    + gb_ + 4);            \
    Pev0 = *reinterpret_cast<const float4*>(refer_embs + gb_);                \
    Pev1 = *reinterpret_cast<const float4*>(refer_embs + gb_ + 4);            \
    Psv0 = *reinterpret_cast<const float4*>(start_embs + gb_);                \
    Psv1 = *reinterpret_cast<const float4*>(start_embs + gb_ + 4);            \
  } while (0)

  LOADQ(0);   // prologue

  for (int it = 0; it < 4; ++it) {
    uint4 bp[4];          // packed bias (row layout), one per quarter
    f32x4 Ch[8];
    #pragma unroll
    for (int nt = 0; nt < 8; ++nt) Ch[nt] = (f32x4){qn[nt], qn[nt], qn[nt], qn[nt]};

    // ================= GEMM1 (four 32-wide d-quarters, pipelined) =========
    #pragma unroll
    for (int Q = 0; Q < 4; ++Q) {
      { // consume prefetched quarter: stage refer_r (one uint4 per lane)
        union { unsigned short u[8]; uint4 v; } pk;
        pk.u[0] = f2bf(Prv0.x); pk.u[1] = f2bf(Prv0.y);
        pk.u[2] = f2bf(Prv0.z); pk.u[3] = f2bf(Prv0.w);
        pk.u[4] = f2bf(Prv1.x); pk.u[5] = f2bf(Prv1.y);
        pk.u[6] = f2bf(Prv1.z); pk.u[7] = f2bf(Prv1.w);
        *reinterpret_cast<uint4*>(&mybuf[srl * WROW + q * 8]) = pk.v;
      }
      { // bias quarter = ev - sv - rv, packed bf16 (row layout, in regs)
        union { unsigned short u[8]; uint4 v; } pk;
        pk.u[0] = f2bf(Pev0.x - Psv0.x - Prv0.x);
        pk.u[1] = f2bf(Pev0.y - Psv0.y - Prv0.y);
        pk.u[2] = f2bf(Pev0.z - Psv0.z - Prv0.z);
        pk.u[3] = f2bf(Pev0.w - Psv0.w - Prv0.w);
        pk.u[4] = f2bf(Pev1.x - Psv1.x - Prv1.x);
        pk.u[5] = f2bf(Pev1.y - Psv1.y - Prv1.y);
        pk.u[6] = f2bf(Pev1.z - Psv1.z - Prv1.z);
        pk.u[7] = f2bf(Pev1.w - Psv1.w - Prv1.w);
        bp[Q] = pk.v;
      }
      { // issue next quarter's loads (values consumed above; stays in
        // flight across the lgkmcnt-only fences below)
        const int fq = it * 4 + Q;
        if (fq + 1 < 16) { LOADQ(fq + 1); }
      }
      asm volatile("s_waitcnt lgkmcnt(0)" ::: "memory");
      const s16x8 af = *reinterpret_cast<const s16x8*>(&mybuf[c * WROW + g * 8]);
      #pragma unroll
      for (int nt = 0; nt < 8; ++nt) {
        s16x8 wf = *reinterpret_cast<const s16x8*>(
            &lds_w1a[(nt * 16 + c) * DIMD + ((Q * 32 + g * 8) ^ swc)]);
        Ch[nt] = __builtin_amdgcn_mfma_f32_16x16x32_bf16(af, wf, Ch[nt], 0, 0, 0);
      }
      asm volatile("s_waitcnt lgkmcnt(0)" ::: "memory");  // af read done before restage
    }

    // ================= GEMM2 (four 32-wide k_hid-quarters) =================
    f32x4 Ca[8];
    #pragma unroll
    for (int nt = 0; nt < 8; ++nt) Ca[nt] = (f32x4){b2v[nt], b2v[nt], b2v[nt], b2v[nt]};
    #pragma unroll
    for (int Q = 0; Q < 4; ++Q) {
      // h quarter (relu, bf16) at C positions: cols 2Q..2Q+1 of the nt grid
      #pragma unroll
      for (int ntl = 0; ntl < 2; ++ntl)
        #pragma unroll
        for (int r = 0; r < 4; ++r)
          mybuf[(rl4 + r) * WROW + ntl * 16 + c] = f2bf(fmaxf(Ch[2 * Q + ntl][r], 0.f));
      asm volatile("s_waitcnt lgkmcnt(0)" ::: "memory");
      const s16x8 hf = *reinterpret_cast<const s16x8*>(&mybuf[c * WROW + g * 8]);
      #pragma unroll
      for (int nt = 0; nt < 8; ++nt) {
        s16x8 wf = *reinterpret_cast<const s16x8*>(
            &lds_w2[(nt * 16 + c) * DIMD + ((Q * 32 + g * 8) ^ swc)]);
        Ca[nt] = __builtin_amdgcn_mfma_f32_16x16x32_bf16(hf, wf, Ca[nt], 0, 0, 0);
      }
      asm volatile("s_waitcnt lgkmcnt(0)" ::: "memory");  // hf read done before restage
    }

    // ================= bias dot + reduce (four quarters) =================
    #pragma unroll
    for (int Q = 0; Q < 4; ++Q) {
      *reinterpret_cast<uint4*>(&mybuf[srl * WROW + q * 8]) = bp[Q];
      asm volatile("s_waitcnt lgkmcnt(0)" ::: "memory");
      #pragma unroll
      for (int ntl = 0; ntl < 2; ++ntl) {
        const int nt = 2 * Q + ntl;
        float s = 0.f;
        #pragma unroll
        for (int r = 0; r < 4; ++r) {
          const float bcv = bf2f(mybuf[(rl4 + r) * WROW + ntl * 16 + c]);
          s = fmaf(Ca[nt][r], bcv, s);
        }
        s += __shfl_xor(s, 16);
        s += __shfl_xor(s, 32);
        acc[nt] += s;
      }
      asm volatile("s_waitcnt lgkmcnt(0)" ::: "memory");  // reads done before restage
    }
  }
#undef LOADQ

  // ---- epilogue
  if (lane < 16) {
    #pragma unroll
    for (int nt = 0; nt < 8; ++nt)
      out[(size_t)b * DIMD + nt * 16 + c] =
          query_emb[(size_t)b * DIMD + nt * 16 + c] + acc[nt];
  }
}

extern "C" void kernel_launch(void* const* d_in, const int* in_sizes, int n_in,
                              void* d_out, int out_size, void* d_ws, size_t ws_size,
                              hipStream_t stream) {
  const float* query_emb  = (const float*)d_in[0];
  const float* offset_emb = (const float*)d_in[1];
  const float* refer_embs = (const float*)d_in[2];
  const float* query_r    = (const float*)d_in[3];
  const float* refer_r    = (const float*)d_in[4];
  const float* start_embs = (const float*)d_in[5];
  const float* W1 = (const float*)d_in[6];
  const float* b1 = (const float*)d_in[7];
  const float* W2 = (const float*)d_in[8];
  const float* b2 = (const float*)d_in[9];
  float* out = (float*)d_out;

  float* qproj = (float*)d_ws;                       // 4096*128 f32 = 2 MB
  unsigned short* w1a_swz =
      (unsigned short*)((char*)d_ws + (size_t)BTOT * DIMD * sizeof(float));
  unsigned short* w2_swz = w1a_swz + 128 * 128;      // +32 KB each

  hipLaunchKernelGGL(prep_kernel, dim3(512), dim3(256), 0, stream,
                     W1, b1, query_r, W2, offset_emb, qproj, w1a_swz, w2_swz, out);
  hipLaunchKernelGGL(main_kernel, dim3(512), dim3(512), 0, stream,
                     query_emb, refer_embs, refer_r, start_embs,
                     b2, qproj, w1a_swz, w2_swz, out);
}